// Round 6
// baseline (190.094 us; speedup 1.0000x reference)
//
#include <hip/hip_runtime.h>

#define NGRIDF 4194304.0f      // 2^22
#define NSEG 5                 // 3.36 MB windows -> resident in 4 MB per-XCD L2
#define PTS 32                 // points per thread
#define BIAS 64.0f             // done-marker: store -(BIAS+rr) in [-97,-31]

// Unaligned-capable 16B vector load (align-4 dwordx4 is legal on gfx9+)
typedef float f32x4u __attribute__((ext_vector_type(4), aligned(4)));

// Branchless point-pass: no exec-mask regions, so all gathers in the
// unrolled stream are independent and can stay in flight together.
// Inactive lanes gather the c[0] line (same-address broadcast: ~free) and
// their result is discarded by the final cndmask. Done points are negative
// so they fail every later test (all lo >= 0).
__device__ __forceinline__ void proc(float& p, float lo,
                                     const float* __restrict__ c) {
    bool  act = (p >= lo);
    // s = x*2^22 exact; sp2 = s+2 replicates the reference's rounding;
    // later subtractions exact -> bitwise-identical basis arguments.
    float s   = p * NGRIDF;
    int   b   = act ? (int)s : 0;          // cvt + cndmask; safe index always
    float sp2 = s + 2.0f;
    float bf  = (float)b;
    float fr  = (sp2 - bf) - 2.0f;         // exact for active lanes, in [0,1)
    float om  = 1.0f - fr;
    float fr2 = fr * fr, fr3 = fr2 * fr;
    float om2 = om * om,  om3 = om2 * om;
    float w1 = fmaf(3.0f, fr3, fmaf(-6.0f, fr2, 4.0f));
    float w2 = fmaf(3.0f, om3, fmaf(-6.0f, om2, 4.0f));
    f32x4u cv = *reinterpret_cast<const f32x4u*>(c + b);   // 1x dwordx4
    float rr = om3 * cv.x;
    rr = fmaf(w1,  cv.y, rr);
    rr = fmaf(w2,  cv.z, rr);
    rr = fmaf(fr3, cv.w, rr);
    p = act ? (-BIAS - rr) : p;            // single cndmask commit
}

// Single-cohort persistent sweep at full occupancy:
// 2048 blocks * 256 thr = 524288 threads = 8 blocks/CU * 4 waves = 32 waves/CU.
// All waves sweep the 5 coefficient segments together (descending lo), so the
// chip's gathers stay inside a ~3.4 MB L2-resident window per pass.
__global__ __launch_bounds__(256, 8) void spline_branchless_kernel(
    const float* __restrict__ x, const float* __restrict__ c,
    float* __restrict__ out)
{
    const int t = threadIdx.x;
    const int blockBase = blockIdx.x * (8 * 256);   // in float4 units
    const float4* __restrict__ x4 = reinterpret_cast<const float4*>(x);
    float4* __restrict__ o4 = reinterpret_cast<float4*>(out);

#define LD(i) float4 v##i = x4[blockBase + (i) * 256 + t];
    LD(0) LD(1) LD(2) LD(3) LD(4) LD(5) LD(6) LD(7)
#undef LD

#define P4(i) proc(v##i.x, lo, c); proc(v##i.y, lo, c); \
              proc(v##i.z, lo, c); proc(v##i.w, lo, c);
    #pragma unroll 1
    for (int seg = NSEG - 1; seg >= 0; --seg) {     // descending sweep
        const float lo = (float)seg * 0.2f;         // last pass lo == 0.0f
        P4(0) P4(1) P4(2) P4(3) P4(4) P4(5) P4(6) P4(7)
    }
#undef P4

    // Decode: stored = -(BIAS+rr); out = -stored - BIAS = rr.
#define ST(i) o4[blockBase + (i) * 256 + t] = \
        make_float4(-v##i.x - BIAS, -v##i.y - BIAS, -v##i.z - BIAS, -v##i.w - BIAS);
    ST(0) ST(1) ST(2) ST(3) ST(4) ST(5) ST(6) ST(7)
#undef ST
}

extern "C" void kernel_launch(void* const* d_in, const int* in_sizes, int n_in,
                              void* d_out, int out_size, void* d_ws, size_t ws_size,
                              hipStream_t stream) {
    const float* x = (const float*)d_in[0];
    const float* c = (const float*)d_in[1];
    float* out = (float*)d_out;
    int n = in_sizes[0];                 // 16777216
    int grid = n / (256 * PTS);          // 2048 blocks -> exactly resident

    spline_branchless_kernel<<<grid, 256, 0, stream>>>(x, c, out);
}